// Round 1
// baseline (8949.187 us; speedup 1.0000x reference)
//
#include <hip/hip_runtime.h>
#include <math.h>

#define BB 8
#define NN 2048
#define KK 20

static __device__ __forceinline__ float lrelu(float h) {
    return h >= 0.f ? h : 0.2f * h;
}

// ---------------- transpose x (B,3,N) -> xt (B,N,4) padded ----------------
__global__ __launch_bounds__(256) void transpose_x(const float* __restrict__ x,
                                                   float* __restrict__ xt) {
    int t = blockIdx.x * 256 + threadIdx.x;
    if (t >= BB * NN) return;
    int b = t / NN, n = t % NN;
    const float* xb = x + (size_t)b * 3 * NN;
    float4 v;
    v.x = xb[n];
    v.y = xb[NN + n];
    v.z = xb[2 * NN + n];
    v.w = 0.f;
    reinterpret_cast<float4*>(xt)[t] = v;
}

// ---------------- per-point squared norm ----------------
__global__ __launch_bounds__(256) void xx_kernel(const float* __restrict__ F, int stride, int off,
                                                 int C, float* __restrict__ xx) {
    int t = blockIdx.x * 256 + threadIdx.x;
    if (t >= BB * NN) return;
    const float* p = F + (size_t)t * stride + off;
    float s = 0.f;
    for (int c = 0; c < C; ++c) { float v = p[c]; s += v * v; }
    xx[t] = s;
}

// ---------------- weight prep: Wm[0..O)=Wa ; Wm[O..2O) = Wb - Wa ----------------
__global__ __launch_bounds__(256) void wmod_kernel(const float* __restrict__ W, int C, int O,
                                                   float* __restrict__ Wm) {
    int t = blockIdx.x * 256 + threadIdx.x;
    if (t >= 2 * O * C) return;
    int o2 = t / C, c = t % C;
    float v;
    if (o2 < O) v = W[(size_t)o2 * 2 * C + c];
    else {
        int o = o2 - O;
        v = W[(size_t)o * 2 * C + C + c] - W[(size_t)o * 2 * C + c];
    }
    Wm[t] = v;
}

// ---------------- KNN top-20 (largest pd = nearest), exact top_k tie semantics ----------------
// block: 256 threads, 32 rows x all 2048 cols, tiles of 128 cols.
template <int C>
__global__ __launch_bounds__(256) void knn_kernel(const float* __restrict__ F, int stride, int off,
                                                  const float* __restrict__ xx,
                                                  int* __restrict__ idxOut) {
    constexpr int ROWS = 32, TM = 128;
    constexpr int CK = (C >= 64) ? 64 : 4;           // K chunk staged at a time
    constexpr int SK = (C >= 64) ? (CK + 4) : 4;     // padded stride (floats)
    constexpr int NKT = (C + CK - 1) / CK;           // # K chunks
    constexpr int KC4 = SK / 4;                      // float4 chunks per row
    constexpr int PDS = TM + 4;                      // pd row stride
    constexpr int mainWords = ROWS * SK + TM * SK + ROWS * PDS + ROWS + TM;
    constexpr int mergeWords = ROWS * 8 * KK * 2;    // 10240
    constexpr int smWords = (mainWords > mergeWords) ? mainWords : mergeWords;
    __shared__ __align__(16) float sm[smWords];

    float* As  = sm;                       // ROWS*SK
    float* Bs  = As + ROWS * SK;           // TM*SK
    float* pdb = Bs + TM * SK;             // ROWS*PDS
    float* xxA = pdb + ROWS * PDS;         // ROWS
    float* xxB = xxA + ROWS;               // TM
    float* mv  = sm;                       // merge alias: ROWS*160 floats
    int*   mi  = (int*)(sm + ROWS * 160);  // ROWS*160 ints

    const int t = threadIdx.x;
    const int blk = blockIdx.x;
    const int b = blk / (NN / ROWS);
    const int n0 = (blk % (NN / ROWS)) * ROWS;
    const float* Fb = F + (size_t)b * NN * stride + off;
    const float* xxb = xx + (size_t)b * NN;

    float tv[KK];
    int ti[KK];
#pragma unroll
    for (int i = 0; i < KK; ++i) { tv[i] = -INFINITY; ti[i] = 0x7fffffff; }
    int minSlot = 0;

    const int r0 = t & 7;    // gemm row group
    const int c0 = t >> 3;   // gemm col group (0..31)
    const int rr = t >> 3;   // topk row (0..31)
    const int sub = t & 7;   // topk sub (0..7)

    for (int mt = 0; mt < NN / TM; ++mt) {
        const int m0 = mt * TM;
        float acc[4][4];
#pragma unroll
        for (int i = 0; i < 4; ++i)
#pragma unroll
            for (int j = 0; j < 4; ++j) acc[i][j] = 0.f;

        for (int kt = 0; kt < NKT; ++kt) {
            __syncthreads();
            for (int i = t; i < ROWS * SK; i += 256) {
                int r = i / SK, c = i % SK;
                int k = kt * CK + c;
                As[i] = (c < CK && k < C) ? Fb[(size_t)(n0 + r) * stride + k] : 0.f;
            }
            for (int i = t; i < TM * SK; i += 256) {
                int r = i / SK, c = i % SK;
                int k = kt * CK + c;
                Bs[i] = (c < CK && k < C) ? Fb[(size_t)(m0 + r) * stride + k] : 0.f;
            }
            if (kt == 0) {
                if (t < ROWS) xxA[t] = xxb[n0 + t];
                if (t < TM) xxB[t] = xxb[m0 + t];
            }
            __syncthreads();

            const float4* As4 = reinterpret_cast<const float4*>(As);
            const float4* Bs4 = reinterpret_cast<const float4*>(Bs);
            for (int c4 = 0; c4 < KC4; ++c4) {
                float4 av[4], bv[4];
#pragma unroll
                for (int i = 0; i < 4; ++i) av[i] = As4[(r0 + 8 * i) * KC4 + c4];
#pragma unroll
                for (int j = 0; j < 4; ++j) bv[j] = Bs4[(c0 + 32 * j) * KC4 + c4];
#pragma unroll
                for (int i = 0; i < 4; ++i)
#pragma unroll
                    for (int j = 0; j < 4; ++j) {
                        acc[i][j] += av[i].x * bv[j].x;
                        acc[i][j] += av[i].y * bv[j].y;
                        acc[i][j] += av[i].z * bv[j].z;
                        acc[i][j] += av[i].w * bv[j].w;
                    }
            }
        }
        // pd = (2*inner - xx_n) - xx_m  (reference association order)
#pragma unroll
        for (int i = 0; i < 4; ++i)
#pragma unroll
            for (int j = 0; j < 4; ++j) {
                int r = r0 + 8 * i, c = c0 + 32 * j;
                pdb[r * PDS + c] = (2.f * acc[i][j] - xxA[r]) - xxB[c];
            }
        __syncthreads();

        // top-k maintenance: 8 threads per row, 16 cols each
        for (int jj = 0; jj < 16; ++jj) {
            int ml = sub * 16 + jj;
            float v = pdb[rr * PDS + ml];
            int m = m0 + ml;
            if (v > tv[minSlot] || (v == tv[minSlot] && m < ti[minSlot])) {
                tv[minSlot] = v; ti[minSlot] = m;
                minSlot = 0;
#pragma unroll
                for (int s = 1; s < KK; ++s)
                    if (tv[s] < tv[minSlot] || (tv[s] == tv[minSlot] && ti[s] > ti[minSlot]))
                        minSlot = s;
            }
        }
        __syncthreads();
    }

    // merge 8 partial top-20 lists per row
    {
        int base = rr * 160 + sub * KK;
#pragma unroll
        for (int s = 0; s < KK; ++s) { mv[base + s] = tv[s]; mi[base + s] = ti[s]; }
    }
    __syncthreads();
    if (t < ROWS) {
        int r = t;
        for (int s = 0; s < KK; ++s) {
            int bq = 0; float bvv = -INFINITY; int bidx = 0x7fffffff;
            for (int q = 0; q < 160; ++q) {
                float v = mv[r * 160 + q]; int id = mi[r * 160 + q];
                if (v > bvv || (v == bvv && id < bidx)) { bvv = v; bidx = id; bq = q; }
            }
            mv[r * 160 + bq] = -INFINITY; mi[r * 160 + bq] = 0x7fffffff;
            idxOut[((size_t)b * NN + n0 + r) * KK + s] = bidx;
        }
    }
}

// ---------------- generic 128x128 tiled fp32 GEMM: out[M,OC] = F[M,K] * Wm[OC,K]^T ----------
__global__ __launch_bounds__(256) void gemm_yz(const float* __restrict__ F, int stride, int off,
                                               const float* __restrict__ Wm, int K, int OC,
                                               float* __restrict__ out) {
    __shared__ float As[128 * 36];
    __shared__ float Ws[128 * 36];
    const int t = threadIdx.x;
    const int row0 = blockIdx.x * 128;
    const int col0 = blockIdx.y * 128;
    float acc[8][8];
#pragma unroll
    for (int i = 0; i < 8; ++i)
#pragma unroll
        for (int j = 0; j < 8; ++j) acc[i][j] = 0.f;

    for (int kt = 0; kt < K; kt += 32) {
        __syncthreads();
        for (int i = t; i < 128 * 32; i += 256) {
            int r = i >> 5, c = i & 31;
            int k = kt + c;
            As[r * 36 + c] = (k < K) ? F[(size_t)(row0 + r) * stride + off + k] : 0.f;
            Ws[r * 36 + c] = (k < K) ? Wm[(size_t)(col0 + r) * K + k] : 0.f;
        }
        __syncthreads();
        const int r0 = t & 15, c0 = t >> 4;
        const float4* As4 = reinterpret_cast<const float4*>(As);
        const float4* Ws4 = reinterpret_cast<const float4*>(Ws);
#pragma unroll
        for (int k4 = 0; k4 < 8; ++k4) {
            float4 a[8], w[8];
#pragma unroll
            for (int i = 0; i < 8; ++i) a[i] = As4[(r0 + 16 * i) * 9 + k4];
#pragma unroll
            for (int j = 0; j < 8; ++j) w[j] = Ws4[(c0 + 16 * j) * 9 + k4];
#pragma unroll
            for (int i = 0; i < 8; ++i)
#pragma unroll
                for (int j = 0; j < 8; ++j) {
                    acc[i][j] += a[i].x * w[j].x;
                    acc[i][j] += a[i].y * w[j].y;
                    acc[i][j] += a[i].z * w[j].z;
                    acc[i][j] += a[i].w * w[j].w;
                }
        }
    }
    const int r0 = t & 15, c0 = t >> 4;
#pragma unroll
    for (int i = 0; i < 8; ++i)
#pragma unroll
        for (int j = 0; j < 8; ++j)
            out[(size_t)(row0 + r0 + 16 * i) * OC + col0 + c0 + 16 * j] = acc[i][j];
}

// ---------------- neighbor gather-max + affine + lrelu -> cat column block ----------------
__global__ __launch_bounds__(256) void neighbor_max(const float* __restrict__ yz,
                                                    const int* __restrict__ idx,
                                                    const float* __restrict__ g,
                                                    const float* __restrict__ bia, int O,
                                                    int outOff, float* __restrict__ cat) {
    int t = blockIdx.x * 256 + threadIdx.x;
    int og = O >> 2;
    if (t >= BB * NN * og) return;
    int o4 = t % og;
    int pn = t / og;
    int bbase = (pn >> 11) << 11;  // batch base row
    const int* ip = idx + (size_t)pn * KK;
    int O2 = O * 2;
    float mx = -INFINITY, my = -INFINITY, mz = -INFINITY, mw = -INFINITY;
    for (int j = 0; j < KK; ++j) {
        int nb = ip[j];
        const float4 v =
            *reinterpret_cast<const float4*>(yz + (size_t)(bbase + nb) * O2 + (o4 << 2));
        mx = fmaxf(mx, v.x); my = fmaxf(my, v.y); mz = fmaxf(mz, v.z); mw = fmaxf(mw, v.w);
    }
    const float4 z = *reinterpret_cast<const float4*>(yz + (size_t)pn * O2 + O + (o4 << 2));
    int o = o4 << 2;
    const float inv = 1.f / sqrtf(1.f + 1e-5f);
    float4 r;
    r.x = lrelu((mx + z.x) * (g[o + 0] * inv) + bia[o + 0]);
    r.y = lrelu((my + z.y) * (g[o + 1] * inv) + bia[o + 1]);
    r.z = lrelu((mz + z.z) * (g[o + 2] * inv) + bia[o + 2]);
    r.w = lrelu((mw + z.w) * (g[o + 3] * inv) + bia[o + 3]);
    *reinterpret_cast<float4*>(cat + (size_t)pn * 512 + outOff + o) = r;
}

// ---------------- final conv (K=512 -> 1024) + affine + lrelu + max over 128-point tile -----
__global__ __launch_bounds__(256) void final_gemm_max(const float* __restrict__ A,
                                                      const float* __restrict__ W,
                                                      const float* __restrict__ g,
                                                      const float* __restrict__ bia,
                                                      float* __restrict__ partial) {
    __shared__ float As[128 * 36];
    __shared__ float Ws[128 * 36];
    __shared__ float red[16 * 132];
    const int t = threadIdx.x;
    const int row0 = blockIdx.x * 128;  // global point row (batches contiguous)
    const int col0 = blockIdx.y * 128;
    float acc[8][8];
#pragma unroll
    for (int i = 0; i < 8; ++i)
#pragma unroll
        for (int j = 0; j < 8; ++j) acc[i][j] = 0.f;

    for (int kt = 0; kt < 512; kt += 32) {
        __syncthreads();
        for (int i = t; i < 128 * 32; i += 256) {
            int r = i >> 5, c = i & 31;
            int k = kt + c;
            As[r * 36 + c] = A[(size_t)(row0 + r) * 512 + k];
            Ws[r * 36 + c] = W[(size_t)(col0 + r) * 512 + k];
        }
        __syncthreads();
        const int r0 = t & 15, c0 = t >> 4;
        const float4* As4 = reinterpret_cast<const float4*>(As);
        const float4* Ws4 = reinterpret_cast<const float4*>(Ws);
#pragma unroll
        for (int k4 = 0; k4 < 8; ++k4) {
            float4 a[8], w[8];
#pragma unroll
            for (int i = 0; i < 8; ++i) a[i] = As4[(r0 + 16 * i) * 9 + k4];
#pragma unroll
            for (int j = 0; j < 8; ++j) w[j] = Ws4[(c0 + 16 * j) * 9 + k4];
#pragma unroll
            for (int i = 0; i < 8; ++i)
#pragma unroll
                for (int j = 0; j < 8; ++j) {
                    acc[i][j] += a[i].x * w[j].x;
                    acc[i][j] += a[i].y * w[j].y;
                    acc[i][j] += a[i].z * w[j].z;
                    acc[i][j] += a[i].w * w[j].w;
                }
        }
    }
    const int r0 = t & 15, c0 = t >> 4;
    const float inv = 1.f / sqrtf(1.f + 1e-5f);
#pragma unroll
    for (int j = 0; j < 8; ++j) {
        int o = col0 + c0 + 16 * j;
        float s = g[o] * inv;
        float bb = bia[o];
        float cm = -INFINITY;
#pragma unroll
        for (int i = 0; i < 8; ++i) {
            float h = acc[i][j] * s + bb;
            h = lrelu(h);
            cm = fmaxf(cm, h);
        }
        red[r0 * 132 + c0 + 16 * j] = cm;
    }
    __syncthreads();
    if (t < 128) {
        float m = -INFINITY;
        for (int q = 0; q < 16; ++q) m = fmaxf(m, red[q * 132 + t]);
        partial[(size_t)blockIdx.x * 1024 + col0 + t] = m;
    }
}

__global__ __launch_bounds__(256) void final_reduce(const float* __restrict__ partial,
                                                    float* __restrict__ out) {
    int t = blockIdx.x * 256 + threadIdx.x;
    if (t >= BB * 1024) return;
    int b = t >> 10, o = t & 1023;
    float m = -INFINITY;
    for (int q = 0; q < 16; ++q) m = fmaxf(m, partial[(size_t)(b * 16 + q) * 1024 + o]);
    out[t] = m;
}

extern "C" void kernel_launch(void* const* d_in, const int* in_sizes, int n_in, void* d_out,
                              int out_size, void* d_ws, size_t ws_size, hipStream_t stream) {
    const float* x  = (const float*)d_in[0];
    const float* W1 = (const float*)d_in[1];
    const float* W2 = (const float*)d_in[2];
    const float* W3 = (const float*)d_in[3];
    const float* W4 = (const float*)d_in[4];
    const float* W5 = (const float*)d_in[5];
    const float* g1 = (const float*)d_in[6];  const float* b1 = (const float*)d_in[7];
    const float* g2 = (const float*)d_in[8];  const float* b2 = (const float*)d_in[9];
    const float* g3 = (const float*)d_in[10]; const float* b3 = (const float*)d_in[11];
    const float* g4 = (const float*)d_in[12]; const float* b4 = (const float*)d_in[13];
    const float* g5 = (const float*)d_in[14]; const float* b5 = (const float*)d_in[15];

    float* ws   = (float*)d_ws;
    float* xt   = ws;                      // B*N*4          = 65536
    float* cat  = xt + 65536;              // B*N*512        = 8388608
    float* yz   = cat + 8388608;           // B*N*512        = 8388608
    float* xxb  = yz + 8388608;            // B*N            = 16384
    int*   idxb = (int*)(xxb + 16384);     // B*N*20         = 327680
    float* wmod = (float*)(idxb + 327680); // <= 512*128     = 65536
    float* part = wmod + 65536;            // 128*1024       = 131072

    dim3 blk(256);

    transpose_x<<<dim3(64), blk, 0, stream>>>(x, xt);

    // ---- layer 1: C=3 (xt, stride 4), O=64 -> cat[0..64)
    xx_kernel<<<dim3(64), blk, 0, stream>>>(xt, 4, 0, 3, xxb);
    knn_kernel<3><<<dim3(512), blk, 0, stream>>>(xt, 4, 0, xxb, idxb);
    wmod_kernel<<<dim3(2), blk, 0, stream>>>(W1, 3, 64, wmod);
    gemm_yz<<<dim3(128, 1), blk, 0, stream>>>(xt, 4, 0, wmod, 3, 128, yz);
    neighbor_max<<<dim3(1024), blk, 0, stream>>>(yz, idxb, g1, b1, 64, 0, cat);

    // ---- layer 2: C=64 (cat off 0), O=64 -> cat[64..128)
    xx_kernel<<<dim3(64), blk, 0, stream>>>(cat, 512, 0, 64, xxb);
    knn_kernel<64><<<dim3(512), blk, 0, stream>>>(cat, 512, 0, xxb, idxb);
    wmod_kernel<<<dim3(32), blk, 0, stream>>>(W2, 64, 64, wmod);
    gemm_yz<<<dim3(128, 1), blk, 0, stream>>>(cat, 512, 0, wmod, 64, 128, yz);
    neighbor_max<<<dim3(1024), blk, 0, stream>>>(yz, idxb, g2, b2, 64, 64, cat);

    // ---- layer 3: C=64 (cat off 64), O=128 -> cat[128..256)
    xx_kernel<<<dim3(64), blk, 0, stream>>>(cat, 512, 64, 64, xxb);
    knn_kernel<64><<<dim3(512), blk, 0, stream>>>(cat, 512, 64, xxb, idxb);
    wmod_kernel<<<dim3(64), blk, 0, stream>>>(W3, 64, 128, wmod);
    gemm_yz<<<dim3(128, 2), blk, 0, stream>>>(cat, 512, 64, wmod, 64, 256, yz);
    neighbor_max<<<dim3(2048), blk, 0, stream>>>(yz, idxb, g3, b3, 128, 128, cat);

    // ---- layer 4: C=128 (cat off 128), O=256 -> cat[256..512)
    xx_kernel<<<dim3(64), blk, 0, stream>>>(cat, 512, 128, 128, xxb);
    knn_kernel<128><<<dim3(512), blk, 0, stream>>>(cat, 512, 128, xxb, idxb);
    wmod_kernel<<<dim3(256), blk, 0, stream>>>(W4, 128, 256, wmod);
    gemm_yz<<<dim3(128, 4), blk, 0, stream>>>(cat, 512, 128, wmod, 128, 512, yz);
    neighbor_max<<<dim3(4096), blk, 0, stream>>>(yz, idxb, g4, b4, 256, 256, cat);

    // ---- final: 512 -> 1024 conv + lrelu + global max over N
    final_gemm_max<<<dim3(128, 8), blk, 0, stream>>>(cat, W5, g5, b5, part);
    final_reduce<<<dim3(32), blk, 0, stream>>>(part, (float*)d_out);
}

// Round 2
// 2773.686 us; speedup vs baseline: 3.2265x; 3.2265x over previous
//
#include <hip/hip_runtime.h>
#include <math.h>

#define BB 8
#define NN 2048
#define KK 20

static __device__ __forceinline__ float lrelu(float h) {
    return h >= 0.f ? h : 0.2f * h;
}

// ---------------- transpose x (B,3,N) -> xt (B,N,4) padded ----------------
__global__ __launch_bounds__(256) void transpose_x(const float* __restrict__ x,
                                                   float* __restrict__ xt) {
    int t = blockIdx.x * 256 + threadIdx.x;
    if (t >= BB * NN) return;
    int b = t / NN, n = t % NN;
    const float* xb = x + (size_t)b * 3 * NN;
    float4 v;
    v.x = xb[n];
    v.y = xb[NN + n];
    v.z = xb[2 * NN + n];
    v.w = 0.f;
    reinterpret_cast<float4*>(xt)[t] = v;
}

// ---------------- per-point squared norm ----------------
__global__ __launch_bounds__(256) void xx_kernel(const float* __restrict__ F, int stride, int off,
                                                 int C, float* __restrict__ xx) {
    int t = blockIdx.x * 256 + threadIdx.x;
    if (t >= BB * NN) return;
    const float* p = F + (size_t)t * stride + off;
    float s = 0.f;
    for (int c = 0; c < C; ++c) { float v = p[c]; s += v * v; }
    xx[t] = s;
}

// ---------------- weight prep: Wm[0..O)=Wa ; Wm[O..2O) = Wb - Wa ----------------
__global__ __launch_bounds__(256) void wmod_kernel(const float* __restrict__ W, int C, int O,
                                                   float* __restrict__ Wm) {
    int t = blockIdx.x * 256 + threadIdx.x;
    if (t >= 2 * O * C) return;
    int o2 = t / C, c = t % C;
    float v;
    if (o2 < O) v = W[(size_t)o2 * 2 * C + c];
    else {
        int o = o2 - O;
        v = W[(size_t)o * 2 * C + C + c] - W[(size_t)o * 2 * C + c];
    }
    Wm[t] = v;
}

// ---------------- KNN top-20 (largest pd = nearest), exact top_k tie semantics ----------------
// block: 256 threads, 32 rows x all 2048 cols, tiles of 128 cols.
// Top-k lists live in VGPRs (sorted desc, static-index unrolled insertion).
template <int C>
__global__ __launch_bounds__(256) void knn_kernel(const float* __restrict__ F, int stride, int off,
                                                  const float* __restrict__ xx,
                                                  int* __restrict__ idxOut) {
    constexpr int ROWS = 32, TM = 128;
    constexpr int CK = (C >= 64) ? 32 : 4;           // K chunk staged at a time
    constexpr int SK = (C >= 64) ? (CK + 4) : 4;     // padded stride (floats)
    constexpr int NKT = (C + CK - 1) / CK;           // # K chunks
    constexpr int S4 = SK / 4;                       // float4 stride per row
    constexpr int C4 = CK / 4;                       // float4 compute chunks
    constexpr int PDS = TM + 4;                      // pd row stride
    constexpr int mainWords = ROWS * SK + TM * SK + ROWS * PDS + ROWS + TM;
    constexpr int mergeWords = ROWS * 8 * KK * 2;    // 10240
    constexpr int smWords = (mainWords > mergeWords) ? mainWords : mergeWords;
    __shared__ __align__(16) float sm[smWords];

    float* As  = sm;                       // ROWS*SK
    float* Bs  = As + ROWS * SK;           // TM*SK
    float* pdb = Bs + TM * SK;             // ROWS*PDS
    float* xxA = pdb + ROWS * PDS;         // ROWS
    float* xxB = xxA + ROWS;               // TM
    float* mv  = sm;                       // merge alias: row*160 + sub*20 + s
    int*   mi  = (int*)(sm + ROWS * 160);  // same layout

    const int t = threadIdx.x;
    const int blk = blockIdx.x;
    const int b = blk / (NN / ROWS);
    const int n0 = (blk % (NN / ROWS)) * ROWS;
    const float* Fb = F + (size_t)b * NN * stride + off;
    const float* xxb = xx + (size_t)b * NN;

    // sorted descending top-20, all in registers
    float tv[KK];
    int ti[KK];
#pragma unroll
    for (int i = 0; i < KK; ++i) { tv[i] = -INFINITY; ti[i] = 0x7fffffff; }

    const int r0 = t & 7;    // gemm row group
    const int c0 = t >> 3;   // gemm col group (0..31)
    const int rr = t >> 3;   // topk row (0..31)
    const int sub = t & 7;   // topk sub (0..7)

    for (int mt = 0; mt < NN / TM; ++mt) {
        const int m0 = mt * TM;
        float acc[4][4];
#pragma unroll
        for (int i = 0; i < 4; ++i)
#pragma unroll
            for (int j = 0; j < 4; ++j) acc[i][j] = 0.f;

        for (int kt = 0; kt < NKT; ++kt) {
            __syncthreads();
            for (int i = t; i < ROWS * SK; i += 256) {
                int r = i / SK, c = i % SK;
                int k = kt * CK + c;
                As[i] = (c < CK && k < C) ? Fb[(size_t)(n0 + r) * stride + k] : 0.f;
            }
            for (int i = t; i < TM * SK; i += 256) {
                int r = i / SK, c = i % SK;
                int k = kt * CK + c;
                Bs[i] = (c < CK && k < C) ? Fb[(size_t)(m0 + r) * stride + k] : 0.f;
            }
            if (kt == 0) {
                if (t < ROWS) xxA[t] = xxb[n0 + t];
                if (t < TM) xxB[t] = xxb[m0 + t];
            }
            __syncthreads();

            const float4* As4 = reinterpret_cast<const float4*>(As);
            const float4* Bs4 = reinterpret_cast<const float4*>(Bs);
#pragma unroll
            for (int c4 = 0; c4 < C4; ++c4) {
                float4 av[4], bv[4];
#pragma unroll
                for (int i = 0; i < 4; ++i) av[i] = As4[(r0 + 8 * i) * S4 + c4];
#pragma unroll
                for (int j = 0; j < 4; ++j) bv[j] = Bs4[(c0 + 32 * j) * S4 + c4];
#pragma unroll
                for (int i = 0; i < 4; ++i)
#pragma unroll
                    for (int j = 0; j < 4; ++j) {
                        acc[i][j] += av[i].x * bv[j].x;
                        acc[i][j] += av[i].y * bv[j].y;
                        acc[i][j] += av[i].z * bv[j].z;
                        acc[i][j] += av[i].w * bv[j].w;
                    }
            }
        }
        // pd = (2*inner - xx_n) - xx_m  (reference association order)
#pragma unroll
        for (int i = 0; i < 4; ++i)
#pragma unroll
            for (int j = 0; j < 4; ++j) {
                int r = r0 + 8 * i, c = c0 + 32 * j;
                pdb[r * PDS + c] = (2.f * acc[i][j] - xxA[r]) - xxB[c];
            }
        __syncthreads();

        // top-k maintenance: 8 threads per row, 16 cols each (col = sub + 8*jj, 2-way banks)
        for (int jj = 0; jj < 16; ++jj) {
            int ml = sub + 8 * jj;
            float v = pdb[rr * PDS + ml];
            int m = m0 + ml;
            bool acc2 = (v > tv[KK - 1]) || (v == tv[KK - 1] && m < ti[KK - 1]);
            if (acc2) {
                float cv = v; int ci = m;
#pragma unroll
                for (int s = 0; s < KK; ++s) {
                    bool better = (cv > tv[s]) || (cv == tv[s] && ci < ti[s]);
                    float nv = better ? cv : tv[s];
                    int   ni = better ? ci : ti[s];
                    float ov = better ? tv[s] : cv;
                    int   oi = better ? ti[s] : ci;
                    tv[s] = nv; ti[s] = ni; cv = ov; ci = oi;
                }
            }
        }
        __syncthreads();
    }

    // stage 8 sorted lists per row, then 8-way merge (heads packed in u64)
    {
        int base = rr * 160 + sub * KK;
#pragma unroll
        for (int s = 0; s < KK; ++s) { mv[base + s] = tv[s]; mi[base + s] = ti[s]; }
    }
    __syncthreads();
    if (t < ROWS) {
        int r = t;
        unsigned long long heads = 0ull;
        int* op = idxOut + ((size_t)b * NN + n0 + r) * KK;
        for (int s = 0; s < KK; ++s) {
            float bvv = -INFINITY; int bidx = 0x7fffffff; int bq = 0;
#pragma unroll
            for (int q = 0; q < 8; ++q) {
                int hq = (int)((heads >> (8 * q)) & 0xff);
                float v = mv[r * 160 + q * KK + hq];
                int id = mi[r * 160 + q * KK + hq];
                bool better = (v > bvv) || (v == bvv && id < bidx);
                bvv = better ? v : bvv;
                bidx = better ? id : bidx;
                bq = better ? q : bq;
            }
            op[s] = bidx;
            heads += 1ull << (8 * bq);
        }
    }
}

// ---------------- generic 128x128 tiled fp32 GEMM: out[M,OC] = F[M,K] * Wm[OC,K]^T ----------
__global__ __launch_bounds__(256) void gemm_yz(const float* __restrict__ F, int stride, int off,
                                               const float* __restrict__ Wm, int K, int OC,
                                               float* __restrict__ out) {
    __shared__ float As[128 * 36];
    __shared__ float Ws[128 * 36];
    const int t = threadIdx.x;
    const int row0 = blockIdx.x * 128;
    const int col0 = blockIdx.y * 128;
    float acc[8][8];
#pragma unroll
    for (int i = 0; i < 8; ++i)
#pragma unroll
        for (int j = 0; j < 8; ++j) acc[i][j] = 0.f;

    for (int kt = 0; kt < K; kt += 32) {
        __syncthreads();
        for (int i = t; i < 128 * 32; i += 256) {
            int r = i >> 5, c = i & 31;
            int k = kt + c;
            As[r * 36 + c] = (k < K) ? F[(size_t)(row0 + r) * stride + off + k] : 0.f;
            Ws[r * 36 + c] = (k < K) ? Wm[(size_t)(col0 + r) * K + k] : 0.f;
        }
        __syncthreads();
        const int r0 = t & 15, c0 = t >> 4;
        const float4* As4 = reinterpret_cast<const float4*>(As);
        const float4* Ws4 = reinterpret_cast<const float4*>(Ws);
#pragma unroll
        for (int k4 = 0; k4 < 8; ++k4) {
            float4 a[8], w[8];
#pragma unroll
            for (int i = 0; i < 8; ++i) a[i] = As4[(r0 + 16 * i) * 9 + k4];
#pragma unroll
            for (int j = 0; j < 8; ++j) w[j] = Ws4[(c0 + 16 * j) * 9 + k4];
#pragma unroll
            for (int i = 0; i < 8; ++i)
#pragma unroll
                for (int j = 0; j < 8; ++j) {
                    acc[i][j] += a[i].x * w[j].x;
                    acc[i][j] += a[i].y * w[j].y;
                    acc[i][j] += a[i].z * w[j].z;
                    acc[i][j] += a[i].w * w[j].w;
                }
        }
    }
    const int r0 = t & 15, c0 = t >> 4;
#pragma unroll
    for (int i = 0; i < 8; ++i)
#pragma unroll
        for (int j = 0; j < 8; ++j)
            out[(size_t)(row0 + r0 + 16 * i) * OC + col0 + c0 + 16 * j] = acc[i][j];
}

// ---------------- neighbor gather-max + affine + lrelu -> cat column block ----------------
__global__ __launch_bounds__(256) void neighbor_max(const float* __restrict__ yz,
                                                    const int* __restrict__ idx,
                                                    const float* __restrict__ g,
                                                    const float* __restrict__ bia, int O,
                                                    int outOff, float* __restrict__ cat) {
    int t = blockIdx.x * 256 + threadIdx.x;
    int og = O >> 2;
    if (t >= BB * NN * og) return;
    int o4 = t % og;
    int pn = t / og;
    int bbase = (pn >> 11) << 11;  // batch base row
    const int* ip = idx + (size_t)pn * KK;
    int O2 = O * 2;
    float mx = -INFINITY, my = -INFINITY, mz = -INFINITY, mw = -INFINITY;
    for (int j = 0; j < KK; ++j) {
        int nb = ip[j];
        const float4 v =
            *reinterpret_cast<const float4*>(yz + (size_t)(bbase + nb) * O2 + (o4 << 2));
        mx = fmaxf(mx, v.x); my = fmaxf(my, v.y); mz = fmaxf(mz, v.z); mw = fmaxf(mw, v.w);
    }
    const float4 z = *reinterpret_cast<const float4*>(yz + (size_t)pn * O2 + O + (o4 << 2));
    int o = o4 << 2;
    const float inv = 1.f / sqrtf(1.f + 1e-5f);
    float4 r;
    r.x = lrelu((mx + z.x) * (g[o + 0] * inv) + bia[o + 0]);
    r.y = lrelu((my + z.y) * (g[o + 1] * inv) + bia[o + 1]);
    r.z = lrelu((mz + z.z) * (g[o + 2] * inv) + bia[o + 2]);
    r.w = lrelu((mw + z.w) * (g[o + 3] * inv) + bia[o + 3]);
    *reinterpret_cast<float4*>(cat + (size_t)pn * 512 + outOff + o) = r;
}

// ---------------- final conv (K=512 -> 1024) + affine + lrelu + max over 128-point tile -----
__global__ __launch_bounds__(256) void final_gemm_max(const float* __restrict__ A,
                                                      const float* __restrict__ W,
                                                      const float* __restrict__ g,
                                                      const float* __restrict__ bia,
                                                      float* __restrict__ partial) {
    __shared__ float As[128 * 36];
    __shared__ float Ws[128 * 36];
    __shared__ float red[16 * 132];
    const int t = threadIdx.x;
    const int row0 = blockIdx.x * 128;  // global point row (batches contiguous)
    const int col0 = blockIdx.y * 128;
    float acc[8][8];
#pragma unroll
    for (int i = 0; i < 8; ++i)
#pragma unroll
        for (int j = 0; j < 8; ++j) acc[i][j] = 0.f;

    for (int kt = 0; kt < 512; kt += 32) {
        __syncthreads();
        for (int i = t; i < 128 * 32; i += 256) {
            int r = i >> 5, c = i & 31;
            int k = kt + c;
            As[r * 36 + c] = A[(size_t)(row0 + r) * 512 + k];
            Ws[r * 36 + c] = W[(size_t)(col0 + r) * 512 + k];
        }
        __syncthreads();
        const int r0 = t & 15, c0 = t >> 4;
        const float4* As4 = reinterpret_cast<const float4*>(As);
        const float4* Ws4 = reinterpret_cast<const float4*>(Ws);
#pragma unroll
        for (int k4 = 0; k4 < 8; ++k4) {
            float4 a[8], w[8];
#pragma unroll
            for (int i = 0; i < 8; ++i) a[i] = As4[(r0 + 16 * i) * 9 + k4];
#pragma unroll
            for (int j = 0; j < 8; ++j) w[j] = Ws4[(c0 + 16 * j) * 9 + k4];
#pragma unroll
            for (int i = 0; i < 8; ++i)
#pragma unroll
                for (int j = 0; j < 8; ++j) {
                    acc[i][j] += a[i].x * w[j].x;
                    acc[i][j] += a[i].y * w[j].y;
                    acc[i][j] += a[i].z * w[j].z;
                    acc[i][j] += a[i].w * w[j].w;
                }
        }
    }
    const int r0 = t & 15, c0 = t >> 4;
    const float inv = 1.f / sqrtf(1.f + 1e-5f);
#pragma unroll
    for (int j = 0; j < 8; ++j) {
        int o = col0 + c0 + 16 * j;
        float s = g[o] * inv;
        float bb = bia[o];
        float cm = -INFINITY;
#pragma unroll
        for (int i = 0; i < 8; ++i) {
            float h = acc[i][j] * s + bb;
            h = lrelu(h);
            cm = fmaxf(cm, h);
        }
        red[r0 * 132 + c0 + 16 * j] = cm;
    }
    __syncthreads();
    if (t < 128) {
        float m = -INFINITY;
        for (int q = 0; q < 16; ++q) m = fmaxf(m, red[q * 132 + t]);
        partial[(size_t)blockIdx.x * 1024 + col0 + t] = m;
    }
}

__global__ __launch_bounds__(256) void final_reduce(const float* __restrict__ partial,
                                                    float* __restrict__ out) {
    int t = blockIdx.x * 256 + threadIdx.x;
    if (t >= BB * 1024) return;
    int b = t >> 10, o = t & 1023;
    float m = -INFINITY;
    for (int q = 0; q < 16; ++q) m = fmaxf(m, partial[(size_t)(b * 16 + q) * 1024 + o]);
    out[t] = m;
}

extern "C" void kernel_launch(void* const* d_in, const int* in_sizes, int n_in, void* d_out,
                              int out_size, void* d_ws, size_t ws_size, hipStream_t stream) {
    const float* x  = (const float*)d_in[0];
    const float* W1 = (const float*)d_in[1];
    const float* W2 = (const float*)d_in[2];
    const float* W3 = (const float*)d_in[3];
    const float* W4 = (const float*)d_in[4];
    const float* W5 = (const float*)d_in[5];
    const float* g1 = (const float*)d_in[6];  const float* b1 = (const float*)d_in[7];
    const float* g2 = (const float*)d_in[8];  const float* b2 = (const float*)d_in[9];
    const float* g3 = (const float*)d_in[10]; const float* b3 = (const float*)d_in[11];
    const float* g4 = (const float*)d_in[12]; const float* b4 = (const float*)d_in[13];
    const float* g5 = (const float*)d_in[14]; const float* b5 = (const float*)d_in[15];

    float* ws   = (float*)d_ws;
    float* xt   = ws;                      // B*N*4          = 65536
    float* cat  = xt + 65536;              // B*N*512        = 8388608
    float* yz   = cat + 8388608;           // B*N*512        = 8388608
    float* xxb  = yz + 8388608;            // B*N            = 16384
    int*   idxb = (int*)(xxb + 16384);     // B*N*20         = 327680
    float* wmod = (float*)(idxb + 327680); // <= 512*128     = 65536
    float* part = wmod + 65536;            // 128*1024       = 131072

    dim3 blk(256);

    transpose_x<<<dim3(64), blk, 0, stream>>>(x, xt);

    // ---- layer 1: C=3 (xt, stride 4), O=64 -> cat[0..64)
    xx_kernel<<<dim3(64), blk, 0, stream>>>(xt, 4, 0, 3, xxb);
    knn_kernel<3><<<dim3(512), blk, 0, stream>>>(xt, 4, 0, xxb, idxb);
    wmod_kernel<<<dim3(2), blk, 0, stream>>>(W1, 3, 64, wmod);
    gemm_yz<<<dim3(128, 1), blk, 0, stream>>>(xt, 4, 0, wmod, 3, 128, yz);
    neighbor_max<<<dim3(1024), blk, 0, stream>>>(yz, idxb, g1, b1, 64, 0, cat);

    // ---- layer 2: C=64 (cat off 0), O=64 -> cat[64..128)
    xx_kernel<<<dim3(64), blk, 0, stream>>>(cat, 512, 0, 64, xxb);
    knn_kernel<64><<<dim3(512), blk, 0, stream>>>(cat, 512, 0, xxb, idxb);
    wmod_kernel<<<dim3(32), blk, 0, stream>>>(W2, 64, 64, wmod);
    gemm_yz<<<dim3(128, 1), blk, 0, stream>>>(cat, 512, 0, wmod, 64, 128, yz);
    neighbor_max<<<dim3(1024), blk, 0, stream>>>(yz, idxb, g2, b2, 64, 64, cat);

    // ---- layer 3: C=64 (cat off 64), O=128 -> cat[128..256)
    xx_kernel<<<dim3(64), blk, 0, stream>>>(cat, 512, 64, 64, xxb);
    knn_kernel<64><<<dim3(512), blk, 0, stream>>>(cat, 512, 64, xxb, idxb);
    wmod_kernel<<<dim3(64), blk, 0, stream>>>(W3, 64, 128, wmod);
    gemm_yz<<<dim3(128, 2), blk, 0, stream>>>(cat, 512, 64, wmod, 64, 256, yz);
    neighbor_max<<<dim3(2048), blk, 0, stream>>>(yz, idxb, g3, b3, 128, 128, cat);

    // ---- layer 4: C=128 (cat off 128), O=256 -> cat[256..512)
    xx_kernel<<<dim3(64), blk, 0, stream>>>(cat, 512, 128, 128, xxb);
    knn_kernel<128><<<dim3(512), blk, 0, stream>>>(cat, 512, 128, xxb, idxb);
    wmod_kernel<<<dim3(256), blk, 0, stream>>>(W4, 128, 256, wmod);
    gemm_yz<<<dim3(128, 4), blk, 0, stream>>>(cat, 512, 128, wmod, 128, 512, yz);
    neighbor_max<<<dim3(4096), blk, 0, stream>>>(yz, idxb, g4, b4, 256, 256, cat);

    // ---- final: 512 -> 1024 conv + lrelu + global max over N
    final_gemm_max<<<dim3(128, 8), blk, 0, stream>>>(cat, W5, g5, b5, part);
    final_reduce<<<dim3(32), blk, 0, stream>>>(part, (float*)d_out);
}